// Round 3
// baseline (35.680 us; speedup 1.0000x reference)
//
#include <hip/hip_runtime.h>
#include <hip/hip_bf16.h>

// SparseRescale gather, multi-row LDS tile + async global->LDS staging.
//  - scale = 7/10 exactly: 7 output rows <-> 10 input rows, 7 out cols <-> 10
//    in cols. Block = 7 out rows x 448 out cols <=> 10 in rows x 640 in cols;
//    tiles partition BOTH grids exactly (432*7=3024, 12*448=5376, 432*10=4320,
//    12*640=7680), so each input float is staged exactly once globally.
//  - numpy scatter last-write-wins == row-major last-nonzero over each output
//    pixel's <=2x2 disjoint source window; branchless select chain.
//  - staging via __builtin_amdgcn_global_load_lds width=16 (async, no VGPR
//    round trip); one barrier per 3136 outputs.

#define ORIG_W 7680
#define NEW_W  5376

#define ORT 7      // output rows per block
#define OCT 448    // output cols per block (multiple of 64 -> wave-uniform row)
#define IRT 10     // input rows per block
#define ICT 640    // input cols per block
#define NCHUNK (IRT * ICT / 4)   // 1600 16-byte chunks
#define CPR (ICT / 4)            // 160 chunks per input row

__global__ __launch_bounds__(256)
void sparse_rescale_mr(const float* __restrict__ in, float* __restrict__ out) {
    __shared__ float sm[IRT][ICT];     // 25.6 KB

    const int tid = threadIdx.x;
    const int p = blockIdx.x;          // 0..11  (x tile)
    const int q = blockIdx.y;          // 0..431 (y tile)

    const float* gbase = in + (size_t)(10 * q) * ORIG_W + 640 * p;

    // Stage 10 rows x 640 floats = 1600 float4 chunks, async direct-to-LDS.
    #pragma unroll
    for (int i = 0; i < 7; ++i) {
        int idx = tid + 256 * i;                 // linear in tid -> LDS dest
        if (idx < NCHUNK) {                      // i==6: wave 0 only, fully active
            int r  = idx / CPR;                  // compiler magic-mul
            int c4 = idx - r * CPR;
            const float* src = gbase + (size_t)r * ORIG_W + c4 * 4;
            __builtin_amdgcn_global_load_lds(
                (const __attribute__((address_space(1))) void*)src,
                (__attribute__((address_space(3))) void*)&sm[r][c4 * 4],
                16, 0, 0);
        }
    }
    __syncthreads();   // drains vmcnt(0): staged data visible

    const size_t obase = (size_t)(7 * q) * NEW_W + 448 * p;

    // 3136 outputs, 13 iterations of 256 (last: 64 threads).
    #pragma unroll
    for (int k = 0; k < 13; ++k) {
        int j = tid + 256 * k;
        if (j < ORT * OCT) {
            int orow = j / OCT;                  // wave-uniform (OCT % 64 == 0)
            int oc   = j - orow * OCT;
            // local source window, rows [r0, r1] cols [x0, x1] (inclusive),
            // 1-2 each; duplicate read when width/height == 1.
            int r0 = (10 * orow + 6) / 7;
            int r1 = (10 * orow + 16) / 7 - 1;
            int x0 = (10 * oc + 6) / 7;
            int x1 = (10 * oc + 16) / 7 - 1;

            float a0 = sm[r0][x0], a1 = sm[r0][x1];
            float b0 = sm[r1][x0], b1 = sm[r1][x1];

            float v = 0.0f;                      // row-major last nonzero wins
            if (a0 != 0.0f) v = a0;
            if (a1 != 0.0f) v = a1;
            if (b0 != 0.0f) v = b0;
            if (b1 != 0.0f) v = b1;

            out[obase + (size_t)orow * NEW_W + oc] = v;
        }
    }
}

extern "C" void kernel_launch(void* const* d_in, const int* in_sizes, int n_in,
                              void* d_out, int out_size, void* d_ws, size_t ws_size,
                              hipStream_t stream) {
    const float* arr = (const float*)d_in[0];
    float* out = (float*)d_out;

    dim3 block(256, 1, 1);
    dim3 grid(12, 432, 1);   // 12*448 = 5376 cols, 432*7 = 3024 rows
    sparse_rescale_mr<<<grid, block, 0, stream>>>(arr, out);
}

// Round 4
// 33.679 us; speedup vs baseline: 1.0594x; 1.0594x over previous
//
#include <hip/hip_runtime.h>
#include <hip/hip_bf16.h>

// SparseRescale gather — R2 structure (best so far, 33.9us) + async
// global_load_lds staging.
//  - scale = 7/10 exactly: output (oy,ox) owns disjoint source window
//    rows [ceil(10oy/7), ceil(10(oy+1)/7)) x cols [ceil(10ox/7), ceil(10(ox+1)/7));
//    windows partition the source grid, so each input float is staged once.
//  - numpy scatter last-write-wins == row-major last-nonzero over the <=2x2
//    window; branchless select chain (duplicate reads when window is 1-wide).
//  - block = 1 output row x 1792 cols <=> 1-2 input rows x 2560 cols (20KB LDS,
//    8 blocks/CU -> full occupancy).
//  - staging: __builtin_amdgcn_global_load_lds width=16, lane-linear dest
//    (wave-uniform base + lane*16 -- required layout), no VGPR round-trip.

#define ORIG_W 7680
#define NEW_W  5376
#define TILE_OUT 1792   // 7*256
#define TILE_IN  2560   // TILE_OUT*10/7, exact
#define CPR (TILE_IN / 4)   // 640 float4 chunks per input row

__global__ __launch_bounds__(256)
void sparse_rescale_async(const float* __restrict__ in, float* __restrict__ out) {
    __shared__ float sm[2][TILE_IN];     // 20 KB, unpadded (lane-linear dest)

    const int tid  = threadIdx.x;
    const int tile = blockIdx.x;         // 0..2
    const int oy   = blockIdx.y;         // 0..3023

    const int y0    = (10 * oy + 6) / 7;       // block-uniform
    const int nrows = (10 * oy + 16) / 7 - y0; // 1 or 2
    const int xin0  = tile * TILE_IN;

    // Stage nrows rows x 640 float4 chunks, async direct-to-LDS.
    for (int r = 0; r < nrows; ++r) {          // block-uniform trip count
        const float* src = in + (size_t)(y0 + r) * ORIG_W + xin0;
        #pragma unroll
        for (int i = 0; i < 3; ++i) {
            int idx = tid + 256 * i;           // lane-linear -> LDS dest ok
            if (idx < CPR) {                   // i==2: threads 0..127
                __builtin_amdgcn_global_load_lds(
                    (const __attribute__((address_space(1))) void*)(src + idx * 4),
                    (__attribute__((address_space(3))) void*)&sm[r][idx * 4],
                    16, 0, 0);
            }
        }
    }
    __syncthreads();   // drains vmcnt: staged data visible

    const int rlast = nrows - 1;               // 0 or 1
    const size_t obase = (size_t)oy * NEW_W + tile * TILE_OUT;

    #pragma unroll
    for (int k = 0; k < 7; ++k) {
        const int oxl = tid + 256 * k;         // 0..1791
        const int x0  = (10 * oxl + 6) / 7;
        const int x1  = (10 * oxl + 16) / 7 - 1;   // x0 or x0+1

        float a0 = sm[0][x0],     a1 = sm[0][x1];
        float b0 = sm[rlast][x0], b1 = sm[rlast][x1];

        float v = 0.0f;                        // row-major last nonzero wins
        if (a0 != 0.0f) v = a0;
        if (a1 != 0.0f) v = a1;
        if (b0 != 0.0f) v = b0;
        if (b1 != 0.0f) v = b1;

        out[obase + oxl] = v;
    }
}

extern "C" void kernel_launch(void* const* d_in, const int* in_sizes, int n_in,
                              void* d_out, int out_size, void* d_ws, size_t ws_size,
                              hipStream_t stream) {
    const float* arr = (const float*)d_in[0];
    float* out = (float*)d_out;

    dim3 block(256, 1, 1);
    dim3 grid(3, 3024, 1);                     // 3*1792 = 5376 output cols
    sparse_rescale_async<<<grid, block, 0, stream>>>(arr, out);
}